// Round 8
// baseline (107.858 us; speedup 1.0000x reference)
//
#include <hip/hip_runtime.h>
#include <math.h>

#define H 512
#define B 2
#define S 256
#define BS 512
#define PI_F 3.14159265358979323846f
#define INV_SQRT_D 0.08838834764831845f  // 1/sqrt(128)

typedef __attribute__((ext_vector_type(8))) short short8;
typedef __attribute__((ext_vector_type(4))) float f32x4;
typedef __attribute__((ext_vector_type(4))) unsigned short ushort4v;

__device__ __forceinline__ unsigned short f2bf(float f) {
    unsigned u = __float_as_uint(f);
    u += 0x7FFFu + ((u >> 16) & 1u);      // round-to-nearest-even
    return (unsigned short)(u >> 16);
}
__device__ __forceinline__ float bf2f(unsigned short u) {
    return __uint_as_float((unsigned)u << 16);
}

__device__ __forceinline__ void softmax3(const float* sw, float& w0, float& w1, float& w2)
{
    float s0 = sw[0], s1 = sw[1], s2 = sw[2];
    float mx = fmaxf(s0, fmaxf(s1, s2));
    float e0 = __expf(s0 - mx), e1 = __expf(s1 - mx), e2 = __expf(s2 - mx);
    float inv = 1.f / (e0 + e1 + e2);
    w0 = e0 * inv; w1 = e1 * inv; w2 = e2 * inv;
}

__device__ __forceinline__ void gload16(const unsigned short* g, void* l) {
    __builtin_amdgcn_global_load_lds(
        (const __attribute__((address_space(1))) unsigned int*)g,
        (__attribute__((address_space(3))) unsigned int*)l,
        16, 0, 0);
}

// ------------------------------------------------------------------
// Shared MFMA GEMM body (64x64 tile, BK=64, 4 waves, dbuf LDS,
// 2-phase prefetch, XOR-swizzled LDS both-sides).
// EPI: 1 = fp32 out + qkvt col-activation + bias + bf16 v-copy to aux
//      3 = fp32 partial out, no bias
//      4 = bf16 out, no bias
// ------------------------------------------------------------------
template<int EPI>
__device__ __forceinline__ void gemm_body(
    const unsigned short* __restrict__ Ablk, int lda,
    const unsigned short* __restrict__ Btblk, int ldb,
    const float* __restrict__ bias,
    void* __restrict__ Cout, int ldc,
    int row0, int col0, int nk,
    unsigned short (*As)[4096], unsigned short (*Bs)[4096],
    unsigned short* __restrict__ aux = nullptr)
{
    const int tid = threadIdx.x;
    const int lane = tid & 63, wave = tid >> 6;
    const int wr = wave >> 1, wc = wave & 1;
    const int rowA = tid >> 3;                               // 0..31
    const int sb = ((tid & 7) << 4) ^ ((rowA & 7) << 4);     // swizzled byte-in-row
    const size_t offA0 = (size_t)rowA * lda + (sb >> 1);
    const size_t offA1 = offA0 + (size_t)32 * lda;
    const size_t offB0 = (size_t)rowA * ldb + (sb >> 1);
    const size_t offB1 = offB0 + (size_t)32 * ldb;
    const unsigned ldsO0 = wave * 1024u, ldsO1 = ldsO0 + 4096u;

    const int fr = lane & 15, grp = lane >> 4;
    int aA[2][2], aB[2][2];
    #pragma unroll
    for (int kk = 0; kk < 2; ++kk)
        #pragma unroll
        for (int f = 0; f < 2; ++f) {
            int ra = wr * 32 + f * 16 + fr;
            int rb = wc * 32 + f * 16 + fr;
            aA[f][kk] = (ra * 128 + kk * 64 + grp * 16) ^ ((ra & 7) << 4);
            aB[f][kk] = (rb * 128 + kk * 64 + grp * 16) ^ ((rb & 7) << 4);
        }

    auto stage = [&](int buf, int k0) {
        char* ab = (char*)As[buf]; char* bb = (char*)Bs[buf];
        gload16(Ablk  + offA0 + k0, ab + ldsO0);
        gload16(Ablk  + offA1 + k0, ab + ldsO1);
        gload16(Btblk + offB0 + k0, bb + ldsO0);
        gload16(Btblk + offB1 + k0, bb + ldsO1);
    };

    stage(0, 0);
    __syncthreads();
    f32x4 acc[2][2] = {};
    int cur = 0;
    for (int t = 0; t < nk; ++t) {
        if (t + 1 < nk) stage(cur ^ 1, (t + 1) * 64);
        const char* AsB = (const char*)As[cur];
        const char* BsB = (const char*)Bs[cur];
        #pragma unroll
        for (int kk = 0; kk < 2; ++kk) {
            short8 a0 = *(const short8*)(AsB + aA[0][kk]);
            short8 a1 = *(const short8*)(AsB + aA[1][kk]);
            short8 b0 = *(const short8*)(BsB + aB[0][kk]);
            short8 b1 = *(const short8*)(BsB + aB[1][kk]);
            acc[0][0] = __builtin_amdgcn_mfma_f32_16x16x32_bf16(a0, b0, acc[0][0], 0, 0, 0);
            acc[0][1] = __builtin_amdgcn_mfma_f32_16x16x32_bf16(a0, b1, acc[0][1], 0, 0, 0);
            acc[1][0] = __builtin_amdgcn_mfma_f32_16x16x32_bf16(a1, b0, acc[1][0], 0, 0, 0);
            acc[1][1] = __builtin_amdgcn_mfma_f32_16x16x32_bf16(a1, b1, acc[1][1], 0, 0, 0);
        }
        __syncthreads();
        cur ^= 1;
    }

    const int erow = row0 + wr * 32 + grp * 4;
    const int ecol = col0 + wc * 32 + fr;
    #pragma unroll
    for (int fm = 0; fm < 2; ++fm)
        #pragma unroll
        for (int fn = 0; fn < 2; ++fn)
            #pragma unroll
            for (int j = 0; j < 4; ++j) {
                int r = erow + fm * 16 + j;
                int c = ecol + fn * 16;
                float v = acc[fm][fn][j];
                if (EPI == 1) {
                    v += bias[c];
                    if (c < 512)       v = PI_F / (1.f + __expf(-v));
                    else if (c < 1024) v = 1.f  / (1.f + __expf(-v));
                    ((float*)Cout)[(size_t)r * ldc + c] = v;
                    if (c >= 1024 && c < 1536)
                        aux[(size_t)r * 512 + (c - 1024)] = f2bf(v);
                } else if (EPI == 4) {
                    ((unsigned short*)Cout)[(size_t)r * ldc + c] = f2bf(v);
                } else {
                    ((float*)Cout)[(size_t)r * ldc + c] = v;
                }
            }
}

// ------------------------------------------------------------------
// Conv-as-GEMM body, split-K=8; A read from zero-padded xpad[B][264][512]
// (xpad row = s + tap; k = tap*512 + i). fp32 partials to convP[z].
// ------------------------------------------------------------------
__device__ __forceinline__ void conv_body(
    const unsigned short* __restrict__ xpad,
    const unsigned short* __restrict__ WbigT,
    float* __restrict__ convP, int bm, int bn, int z,
    unsigned short (*As)[4096], unsigned short (*Bs)[4096])
{
    const int tid = threadIdx.x;
    const int lane = tid & 63, wave = tid >> 6;
    const int wr = wave >> 1, wc = wave & 1;
    const int rowA = tid >> 3;
    const int sb = ((tid & 7) << 4) ^ ((rowA & 7) << 4);
    const int sbk = sb >> 1;
    const int r0 = bm * 64 + rowA;
    const int base0 = ((r0 >> 8) * 264 + (r0 & 255)) * 512;
    const int r1 = r0 + 32;
    const int base1 = ((r1 >> 8) * 264 + (r1 & 255)) * 512;
    const size_t offB0 = (size_t)(bn * 64 + rowA) * 4608 + sbk;
    const size_t offB1 = offB0 + (size_t)32 * 4608;
    const unsigned ldsO0 = wave * 1024u, ldsO1 = ldsO0 + 4096u;
    const int kstart = z * 576;              // 4608 / 8

    const int fr = lane & 15, grp = lane >> 4;
    int aA[2][2], aB[2][2];
    #pragma unroll
    for (int kk = 0; kk < 2; ++kk)
        #pragma unroll
        for (int f = 0; f < 2; ++f) {
            int ra = wr * 32 + f * 16 + fr;
            int rb = wc * 32 + f * 16 + fr;
            aA[f][kk] = (ra * 128 + kk * 64 + grp * 16) ^ ((ra & 7) << 4);
            aB[f][kk] = (rb * 128 + kk * 64 + grp * 16) ^ ((rb & 7) << 4);
        }

    auto stage = [&](int buf, int k0) {
        int tap = k0 >> 9;
        int ro = tap * 512 + (k0 & 511) + sbk;
        char* ab = (char*)As[buf]; char* bb = (char*)Bs[buf];
        gload16(xpad + base0 + ro, ab + ldsO0);
        gload16(xpad + base1 + ro, ab + ldsO1);
        gload16(WbigT + offB0 + k0, bb + ldsO0);
        gload16(WbigT + offB1 + k0, bb + ldsO1);
    };

    stage(0, kstart);
    __syncthreads();
    f32x4 acc[2][2] = {};
    int cur = 0;
    for (int t = 0; t < 9; ++t) {
        if (t < 8) stage(cur ^ 1, kstart + (t + 1) * 64);
        const char* AsB = (const char*)As[cur];
        const char* BsB = (const char*)Bs[cur];
        #pragma unroll
        for (int kk = 0; kk < 2; ++kk) {
            short8 a0 = *(const short8*)(AsB + aA[0][kk]);
            short8 a1 = *(const short8*)(AsB + aA[1][kk]);
            short8 b0 = *(const short8*)(BsB + aB[0][kk]);
            short8 b1 = *(const short8*)(BsB + aB[1][kk]);
            acc[0][0] = __builtin_amdgcn_mfma_f32_16x16x32_bf16(a0, b0, acc[0][0], 0, 0, 0);
            acc[0][1] = __builtin_amdgcn_mfma_f32_16x16x32_bf16(a0, b1, acc[0][1], 0, 0, 0);
            acc[1][0] = __builtin_amdgcn_mfma_f32_16x16x32_bf16(a1, b0, acc[1][0], 0, 0, 0);
            acc[1][1] = __builtin_amdgcn_mfma_f32_16x16x32_bf16(a1, b1, acc[1][1], 0, 0, 0);
        }
        __syncthreads();
        cur ^= 1;
    }

    float* Cp = convP + (size_t)z * 262144;
    const int erow = bm * 64 + wr * 32 + grp * 4;
    const int ecol = bn * 64 + wc * 32 + fr;
    #pragma unroll
    for (int fm = 0; fm < 2; ++fm)
        #pragma unroll
        for (int fn = 0; fn < 2; ++fn)
            #pragma unroll
            for (int j = 0; j < 4; ++j)
                Cp[(size_t)(erow + fm * 16 + j) * 512 + ecol + fn * 16] = acc[fm][fn][j];
}

// ------------------------------------------------------------------
// Dispatch 1: all prep. Segments by blockIdx (latency-bound FIRST):
// [0,64)        bias_effP[64][512]: block bb covers 24 k's of
//               [bo|bwl|bfc] @ Wproj, fully unrolled
// [64,1088)     WbigT: thread per (o,i), all taps contiguous
// [1088,3136)   32x32-tile transposes: WcatT (1280), WprojT (768)
// [3136,3400)   xpad (zero-padded bf16 x), 4/thread
// [3400,4424)   flat bf16 converts: Wo_b | Wwl_b | Wfc_b, 4/thread
// [4424,4438)   bcat1 + beff + per-channel sincos(phase_shifts)
// ------------------------------------------------------------------
__global__ __launch_bounds__(256)
void prep_all(const float* __restrict__ x,
              const float* __restrict__ Wq, const float* __restrict__ Wk,
              const float* __restrict__ Wv, const float* __restrict__ Wtc,
              const float* __restrict__ Wo, const float* __restrict__ Wwl,
              const float* __restrict__ Wfc, const float* __restrict__ Wproj,
              const float* __restrict__ cw1, const float* __restrict__ cw2,
              const float* __restrict__ cw3, const float* __restrict__ scale_w,
              const float* __restrict__ bq, const float* __restrict__ bk,
              const float* __restrict__ bv, const float* __restrict__ btc,
              const float* __restrict__ cb1, const float* __restrict__ cb2,
              const float* __restrict__ cb3,
              const float* __restrict__ bo, const float* __restrict__ bwl,
              const float* __restrict__ bfc, const float* __restrict__ phase_shifts,
              unsigned short* __restrict__ xpad, unsigned short* __restrict__ WcatT,
              unsigned short* __restrict__ WbigT, unsigned short* __restrict__ WprojT,
              unsigned short* __restrict__ Wo_b, unsigned short* __restrict__ Wwl_b,
              unsigned short* __restrict__ Wfc_b,
              float* __restrict__ bcat1, float* __restrict__ beff,
              float* __restrict__ cps, float* __restrict__ sps,
              float* __restrict__ bias_effP)
{
    int bid = blockIdx.x, tid = threadIdx.x;

    if (bid < 64) {                         // bias_effP[bb][512], 24 k's each
        int k0 = bid * 24;
        float a0 = 0.f, a1 = 0.f;
        #pragma unroll
        for (int m = 0; m < 24; ++m) {
            int k = k0 + m;
            float w = (k < 512) ? bo[k] : (k < 1024) ? bwl[k - 512] : bfc[k - 1024];
            a0 = fmaf(w, Wproj[(size_t)k * 512 + tid], a0);
            a1 = fmaf(w, Wproj[(size_t)k * 512 + tid + 256], a1);
        }
        bias_effP[(size_t)bid * 512 + tid] = a0;
        bias_effP[(size_t)bid * 512 + tid + 256] = a1;
        return;
    }
    bid -= 64;
    if (bid < 1024) {                       // WbigT [512 o][4608 = t*512+i]
        int oi = bid * 256 + tid;           // < 262144
        int o = oi >> 9, i = oi & 511;
        float w0, w1, w2; softmax3(scale_w, w0, w1, w2);
        float wt[9];
        #pragma unroll
        for (int t = 0; t < 9; ++t) wt[t] = w2 * cw3[(size_t)oi * 9 + t];
        #pragma unroll
        for (int t = 0; t < 3; ++t) wt[t + 3] = fmaf(w0, cw1[(size_t)oi * 3 + t], wt[t + 3]);
        #pragma unroll
        for (int t = 0; t < 5; ++t) wt[t + 2] = fmaf(w1, cw2[(size_t)oi * 5 + t], wt[t + 2]);
        unsigned short* dst = WbigT + (size_t)o * 4608 + i;
        #pragma unroll
        for (int t = 0; t < 9; ++t) dst[t * 512] = f2bf(wt[t]);   // coalesced across lanes
        return;
    }
    bid -= 1024;
    if (bid < 2048) {                       // transposes
        __shared__ float tile[32][33];
        int t = bid;
        const float* src; unsigned short* dst;
        int srcld, dstld, ntk, drow0;
        if (t < 256)       {            src = Wq;    srcld = 512;  dst = WcatT;  dstld = 512;  ntk = 16; drow0 = 0; }
        else if (t < 512)  { t -= 256;  src = Wk;    srcld = 512;  dst = WcatT;  dstld = 512;  ntk = 16; drow0 = 512; }
        else if (t < 768)  { t -= 512;  src = Wv;    srcld = 512;  dst = WcatT;  dstld = 512;  ntk = 16; drow0 = 1024; }
        else if (t < 1280) { t -= 768;  src = Wtc;   srcld = 1024; dst = WcatT;  dstld = 512;  ntk = 16; drow0 = 1536; }
        else               { t -= 1280; src = Wproj; srcld = 512;  dst = WprojT; dstld = 1536; ntk = 48; drow0 = 0; }
        int tk = t % ntk, tn = t / ntk;
        int r8 = tid >> 5, c = tid & 31;
        #pragma unroll
        for (int rr = 0; rr < 4; ++rr) {
            int r = r8 + rr * 8;
            tile[r][c] = src[(size_t)(tk * 32 + r) * srcld + tn * 32 + c];
        }
        __syncthreads();
        #pragma unroll
        for (int rr = 0; rr < 4; ++rr) {
            int r = r8 + rr * 8;
            dst[(size_t)(drow0 + tn * 32 + r) * dstld + tk * 32 + c] = f2bf(tile[c][r]);
        }
        return;
    }
    bid -= 2048;
    if (bid < 264) {                        // xpad[B][264][512]
        int e = bid * 1024 + tid * 4;       // < 270336
        int b = e / 135168, rem = e - b * 135168;
        int srow = rem >> 9, i4 = rem & 511;
        int s2 = srow - 4;
        ushort4v pk = {0, 0, 0, 0};
        if (s2 >= 0 && s2 < 256) {
            f32x4 v = *(const f32x4*)&x[((size_t)(b * 256 + s2) << 9) + i4];
            pk[0] = f2bf(v[0]); pk[1] = f2bf(v[1]); pk[2] = f2bf(v[2]); pk[3] = f2bf(v[3]);
        }
        *(ushort4v*)&xpad[e] = pk;
        return;
    }
    bid -= 264;
    if (bid < 1024) {                       // Wo_b | Wwl_b | Wfc_b flat converts
        int f = bid * 1024 + tid * 4;       // < 1048576
        const float* src; unsigned short* dst; int o;
        if (f < 262144)      { src = Wo;  dst = Wo_b;  o = f; }
        else if (f < 524288) { src = Wwl; dst = Wwl_b; o = f - 262144; }
        else                 { src = Wfc; dst = Wfc_b; o = f - 524288; }
        f32x4 v = *(const f32x4*)&src[o];
        ushort4v pk;
        pk[0] = f2bf(v[0]); pk[1] = f2bf(v[1]); pk[2] = f2bf(v[2]); pk[3] = f2bf(v[3]);
        *(ushort4v*)&dst[o] = pk;
        return;
    }
    bid -= 1024;
    {                                       // bcat1 + beff + phase-shift table
        int idx = bid * 256 + tid;
        if (idx < 2560) {
            float v;
            if (idx < 512)       v = bq[idx];
            else if (idx < 1024) v = bk[idx - 512];
            else if (idx < 1536) v = bv[idx - 1024];
            else                 v = btc[idx - 1536];
            bcat1[idx] = v;
        } else if (idx < 3072) {
            int c = idx - 2560;
            float w0, w1, w2; softmax3(scale_w, w0, w1, w2);
            beff[c] = w0 * cb1[c] + w1 * cb2[c] + w2 * cb3[c];
        } else if (idx < 3584) {
            int c = idx - 3072;
            float sn, cn; sincosf(phase_shifts[c], &sn, &cn);
            cps[c] = cn; sps[c] = sn;
        }
    }
}

// ------------------------------------------------------------------
// Dispatch 2: all weight-side + input-side big GEMMs concurrently.
// [0,512)     conv split-K=8 partials
// [512,832)   qkvt = xpad @ WcatT (+bias/sigmoid acts; bf16 v-copy)
// [832,896)   WeffCat_T[:, 0:512]    = WprojT[:,0:512]    @ Wo^T
// [896,960)   WeffCat_T[:, 512:1024] = WprojT[:,512:1024] @ Wwl^T
// [960,1088)  WeffCat_T[:,1024:2048] = WprojT[:,1024:1536]@ Wfc^T
// ------------------------------------------------------------------
__global__ __launch_bounds__(256)
void big_gemms(const unsigned short* __restrict__ xpad,
               const unsigned short* __restrict__ WbigT, float* __restrict__ convP,
               const unsigned short* __restrict__ WcatT, const float* __restrict__ bcat1,
               float* __restrict__ qkvt, unsigned short* __restrict__ vb16,
               const unsigned short* __restrict__ WprojT,
               const unsigned short* __restrict__ Wo_b, const unsigned short* __restrict__ Wwl_b,
               const unsigned short* __restrict__ Wfc_b,
               unsigned short* __restrict__ WeffCat_T)
{
    __shared__ unsigned short As[2][4096], Bs[2][4096];
    int bid = blockIdx.x;
    if (bid < 512) {
        conv_body(xpad, WbigT, convP, (bid >> 3) & 7, bid & 7, bid >> 6, As, Bs);
        return;
    }
    bid -= 512;
    if (bid < 320) {
        int bm = bid / 40, bn = bid % 40;
        int r0 = bm * 64;
        const unsigned short* Axp = xpad + ((size_t)(r0 >> 8) * 264 + (r0 & 255) + 4) * 512;
        gemm_body<1>(Axp, 512, WcatT + (size_t)bn * 64 * 512, 512, bcat1,
                     qkvt, 2560, r0, bn * 64, 8, As, Bs, vb16);
        return;
    }
    bid -= 320;
    if (bid < 64) {
        int bm = bid >> 3, bn = bid & 7;
        gemm_body<4>(WprojT + (size_t)bm * 64 * 1536, 1536, Wo_b + (size_t)bn * 64 * 512, 512,
                     nullptr, WeffCat_T, 2048, bm * 64, bn * 64, 8, As, Bs);
        return;
    }
    bid -= 64;
    if (bid < 64) {
        int bm = bid >> 3, bn = bid & 7;
        gemm_body<4>(WprojT + 512 + (size_t)bm * 64 * 1536, 1536, Wwl_b + (size_t)bn * 64 * 512, 512,
                     nullptr, WeffCat_T + 512, 2048, bm * 64, bn * 64, 8, As, Bs);
        return;
    }
    bid -= 64;
    {   // Wfc part: M=512 (j), N=1024 (nc-channel), K=512
        int bm = bid >> 4, bn = bid & 15;
        gemm_body<4>(WprojT + 1024 + (size_t)bm * 64 * 1536, 1536, Wfc_b + (size_t)bn * 64 * 512, 512,
                     nullptr, WeffCat_T + 1024, 2048, bm * 64, bn * 64, 8, As, Bs);
    }
}

// ------------------------------------------------------------------
// Dispatch 3: branch nonlinears -> A_cat [512 rows][2048] bf16.
// [0,1024)     attn (cos recurrence; 1 exp/iter; bf16 v loads)
// [1024,2048)  phase (transcendental-free: rsqrt + Taylor rotation)
// [2048,3072)  conv split-K=8 reduce
// [3072]       zero split-K semaphores for mid_gemm_ln
// ------------------------------------------------------------------
__global__ __launch_bounds__(256)
void branches(const float* __restrict__ qkvt, const unsigned short* __restrict__ vb16,
              const float* __restrict__ cps, const float* __restrict__ sps,
              const float* __restrict__ convP, const float* __restrict__ beff,
              unsigned short* __restrict__ A_cat, int* __restrict__ cnt)
{
    int bid = blockIdx.x, tid = threadIdx.x;
    if (bid < 1024) {                       // wave attention
        const int bi = bid >> 1;
        const int b = bi >> 8, i = bi & 255;
        const int c = ((bid & 1) << 8) + tid;
        const float* qrow = qkvt + (size_t)bi * 2560;
        const float om = qrow[c];
        const float am = qrow[512 + c] * INV_SQRT_D;
        const float ph = tanhf(qrow[1024 + c]) * PI_F;
        float cosom, sinom, cc, ss;
        sincosf(om, &sinom, &cosom);
        sincosf(fmaf(om, (float)i, ph), &ss, &cc);   // ang at j=0
        const unsigned short* vb = vb16 + (size_t)(b * 256) * 512 + c;
        float se = 0.f, sev = 0.f;
        #pragma unroll 4
        for (int j = 0; j < 256; ++j) {
            float e = __expf(am * cc);
            se += e;
            sev = fmaf(e, bf2f(vb[(size_t)j * 512]), sev);
            float cn = fmaf(cc, cosom, ss * sinom);  // cos(ang - om)
            ss = fmaf(ss, cosom, -cc * sinom);       // sin(ang - om)
            cc = cn;
        }
        A_cat[(size_t)bi * 2048 + c] = f2bf(sev / se);
        return;
    }
    bid -= 1024;
    if (bid < 1024) {                       // phase branch, trans-free
        const int b = bid >> 9, c = bid & 511;
        const int s = tid;
        const float* row = qkvt + (size_t)(b * 256 + s) * 2560 + 1536;
        float re = row[c], im = row[c + 512];
        float hyp2 = fmaf(re, re, im * im);
        float mag = sqrtf(hyp2 + 1e-5f);
        float rh = rsqrtf(fmaxf(hyp2, 1e-30f));
        float cp = re * rh, sp = im * rh;            // cos(p), sin(p)
        float cs = cp, sn = sp;
        #pragma unroll
        for (int m = 32; m; m >>= 1) { cs += __shfl_xor(cs, m); sn += __shfl_xor(sn, m); }
        __shared__ float wred[8];
        int w = s >> 6, l = s & 63;
        if (l == 0) { wred[w] = cs; wred[4 + w] = sn; }
        __syncthreads();
        float mcv = (wred[0] + wred[1] + wred[2] + wred[3]) * (1.f / 256.f);
        float msv = (wred[4] + wred[5] + wred[6] + wred[7]) * (1.f / 256.f);
        float cq = cps[c], sq = sps[c];
        float cpps = cp * cq - sp * sq;              // cos(p+psh)
        float spps = sp * cq + cp * sq;              // sin(p+psh)
        float d = 0.1f * (cpps * mcv + spps * msv);  // |d| <= 0.2
        float d2 = d * d;
        float cosd = 1.f - d2 * (0.5f - d2 * (1.f / 24.f));
        float sind = d * (1.f - d2 * ((1.f / 6.f) - d2 * (1.f / 120.f)));
        float cnp = cp * cosd - sp * sind;           // cos(p + d)
        float snp = sp * cosd + cp * sind;
        size_t o = (size_t)(b * 256 + s) * 2048 + c;
        A_cat[o + 1024] = f2bf(mag * cnp);
        A_cat[o + 1536] = f2bf(mag * snp);
        return;
    }
    bid -= 1024;
    if (bid < 1024) {                       // conv reduce (8 slices)
        int idx = bid * 256 + tid;
        int r = idx >> 9, c = idx & 511;
        float v = beff[c];
        #pragma unroll
        for (int z = 0; z < 8; ++z) v += convP[idx + (size_t)z * 262144];
        A_cat[(size_t)r * 2048 + 512 + c] = f2bf(v);
        return;
    }
    if (tid < 8) cnt[tid] = 0;              // semaphores for mid_gemm_ln
}

// ------------------------------------------------------------------
// Dispatch 4: fused output GEMM (K=2048, split-K=4) + split-K reduce +
// bias_eff + residual + LayerNorm, via per-row-block semaphore: the
// last of 32 blocks (8 bn x 4 z) for row-block bm does the epilogue.
// ------------------------------------------------------------------
__global__ __launch_bounds__(256)
void mid_gemm_ln(const unsigned short* __restrict__ A_cat,
                 const unsigned short* __restrict__ WeffCat_T,
                 float* __restrict__ P, int* __restrict__ cnt,
                 const float* __restrict__ x, const float* __restrict__ bias_effP,
                 const float* __restrict__ bproj,
                 const float* __restrict__ g, const float* __restrict__ bta,
                 float* __restrict__ out)
{
    __shared__ unsigned short As[2][4096], Bs[2][4096];
    int bid = blockIdx.x;
    int z = bid >> 6, bm = (bid >> 3) & 7, bn = bid & 7;
    gemm_body<3>(A_cat + (size_t)bm * 64 * 2048 + z * 512, 2048,
                 WeffCat_T + (size_t)bn * 64 * 2048 + z * 512, 2048,
                 nullptr, P + (size_t)z * 262144, 512, bm * 64, bn * 64, 8, As, Bs);

    // ---- split-K semaphore: last block of this bm does reduce+LN ----
    __threadfence();
    __shared__ int lastFlag;
    int tid = threadIdx.x;
    if (tid == 0) lastFlag = (atomicAdd(&cnt[bm], 1) == 31);
    __syncthreads();
    if (!lastFlag) return;
    __threadfence();

    __shared__ float lds_bias[512], lds_g[512], lds_bt[512];
    for (int c = tid; c < 512; c += 256) {
        float acc = bproj[c];
        #pragma unroll
        for (int p = 0; p < 64; ++p) acc += bias_effP[(size_t)p * 512 + c];
        lds_bias[c] = acc;
        lds_g[c] = g[c];
        lds_bt[c] = bta[c];
    }
    __syncthreads();

    int wave = tid >> 6, lane = tid & 63;
    for (int rr = 0; rr < 16; ++rr) {
        int r = bm * 64 + wave * 16 + rr;
        float v[8];
        float sum = 0.f, sq = 0.f;
        #pragma unroll
        for (int u8 = 0; u8 < 8; ++u8) {
            int c = lane + u8 * 64;
            size_t o = (size_t)r * 512 + c;
            float val = x[o] + lds_bias[c] + P[o] + P[o + 262144] + P[o + 524288] + P[o + 786432];
            v[u8] = val;
            sum += val;
            sq = fmaf(val, val, sq);
        }
        #pragma unroll
        for (int m = 32; m; m >>= 1) { sum += __shfl_xor(sum, m); sq += __shfl_xor(sq, m); }
        float mu = sum * (1.f / 512.f);
        float var = sq * (1.f / 512.f) - mu * mu;
        float inv = rsqrtf(var + 1e-5f);
        #pragma unroll
        for (int u8 = 0; u8 < 8; ++u8) {
            int c = lane + u8 * 64;
            out[(size_t)r * 512 + c] = (v[u8] - mu) * inv * lds_g[c] + lds_bt[c];
        }
    }
}

// ------------------------------------------------------------------
extern "C" void kernel_launch(void* const* d_in, const int* in_sizes, int n_in,
                              void* d_out, int out_size, void* d_ws, size_t ws_size,
                              hipStream_t stream)
{
    const float* x   = (const float*)d_in[0];
    const float* Wq  = (const float*)d_in[1];
    const float* bq  = (const float*)d_in[2];
    const float* Wk  = (const float*)d_in[3];
    const float* bk  = (const float*)d_in[4];
    const float* Wv  = (const float*)d_in[5];
    const float* bv  = (const float*)d_in[6];
    const float* Wo  = (const float*)d_in[7];
    const float* bo  = (const float*)d_in[8];
    const float* cw1 = (const float*)d_in[9];
    const float* cb1 = (const float*)d_in[10];
    const float* cw2 = (const float*)d_in[11];
    const float* cb2 = (const float*)d_in[12];
    const float* cw3 = (const float*)d_in[13];
    const float* cb3 = (const float*)d_in[14];
    const float* scale_w = (const float*)d_in[15];
    const float* Wwl = (const float*)d_in[16];
    const float* bwl = (const float*)d_in[17];
    const float* Wtc = (const float*)d_in[18];
    const float* btc = (const float*)d_in[19];
    const float* Wfc = (const float*)d_in[20];
    const float* bfc = (const float*)d_in[21];
    const float* phase_shifts = (const float*)d_in[22];
    const float* Wproj = (const float*)d_in[23];
    const float* bproj = (const float*)d_in[24];
    const float* ln_g = (const float*)d_in[25];
    const float* ln_b = (const float*)d_in[26];
    float* out = (float*)d_out;

    // ---- workspace layout ----
    float* wsf       = (float*)d_ws;
    float* qkvt      = wsf;                     // 1,310,720 f
    float* convP     = qkvt + 1310720;          // 2,097,152 f (8 x 512x512)
    float* P         = convP + 2097152;         // 1,048,576 f (4 x 512x512)
    float* bias_effP = P + 1048576;             //    32,768 f (64 x 512)
    float* bcat1     = bias_effP + 32768;       //     2,560 f
    float* beff      = bcat1 + 2560;            //       512 f
    float* cps       = beff + 512;              //       512 f
    float* sps       = cps + 512;               //       512 f
    int*   cnt       = (int*)(sps + 512);       //         8 i (+pad to 128)
    unsigned short* u = (unsigned short*)(cnt + 128);
    unsigned short* xpad     = u;                    // 270,336
    unsigned short* WcatT    = xpad + 270336;        // 1,310,720
    unsigned short* WbigT    = WcatT + 1310720;      // 2,359,296
    unsigned short* WprojT   = WbigT + 2359296;      // 786,432
    unsigned short* Wo_b     = WprojT + 786432;      // 262,144
    unsigned short* Wwl_b    = Wo_b + 262144;        // 262,144
    unsigned short* Wfc_b    = Wwl_b + 262144;       // 524,288
    unsigned short* WeffCat_T= Wfc_b + 524288;       // 1,048,576 ([512][2048])
    unsigned short* A_cat    = WeffCat_T + 1048576;  // 1,048,576 ([512][2048])
    unsigned short* vb16     = A_cat + 1048576;      // 262,144

    prep_all<<<4438, 256, 0, stream>>>(x, Wq, Wk, Wv, Wtc, Wo, Wwl, Wfc, Wproj,
                                       cw1, cw2, cw3, scale_w,
                                       bq, bk, bv, btc, cb1, cb2, cb3,
                                       bo, bwl, bfc, phase_shifts,
                                       xpad, WcatT, WbigT, WprojT,
                                       Wo_b, Wwl_b, Wfc_b,
                                       bcat1, beff, cps, sps, bias_effP);

    big_gemms<<<1088, 256, 0, stream>>>(xpad, WbigT, convP, WcatT, bcat1, qkvt, vb16,
                                        WprojT, Wo_b, Wwl_b, Wfc_b, WeffCat_T);

    branches<<<3073, 256, 0, stream>>>(qkvt, vb16, cps, sps, convP, beff, A_cat, cnt);

    mid_gemm_ln<<<256, 256, 0, stream>>>(A_cat, WeffCat_T, P, cnt,
                                         x, bias_effP, bproj, ln_g, ln_b, out);
}

// Round 9
// 63.963 us; speedup vs baseline: 1.6863x; 1.6863x over previous
//
#include <hip/hip_runtime.h>
#include <math.h>

#define H 512
#define B 2
#define S 256
#define BS 512
#define PI_F 3.14159265358979323846f
#define INV_SQRT_D 0.08838834764831845f  // 1/sqrt(128)

typedef __attribute__((ext_vector_type(8))) short short8;
typedef __attribute__((ext_vector_type(4))) float f32x4;
typedef __attribute__((ext_vector_type(4))) unsigned short ushort4v;

__device__ __forceinline__ unsigned short f2bf(float f) {
    unsigned u = __float_as_uint(f);
    u += 0x7FFFu + ((u >> 16) & 1u);      // round-to-nearest-even
    return (unsigned short)(u >> 16);
}
__device__ __forceinline__ float bf2f(unsigned short u) {
    return __uint_as_float((unsigned)u << 16);
}

__device__ __forceinline__ void softmax3(const float* sw, float& w0, float& w1, float& w2)
{
    float s0 = sw[0], s1 = sw[1], s2 = sw[2];
    float mx = fmaxf(s0, fmaxf(s1, s2));
    float e0 = __expf(s0 - mx), e1 = __expf(s1 - mx), e2 = __expf(s2 - mx);
    float inv = 1.f / (e0 + e1 + e2);
    w0 = e0 * inv; w1 = e1 * inv; w2 = e2 * inv;
}

__device__ __forceinline__ void gload16(const unsigned short* g, void* l) {
    __builtin_amdgcn_global_load_lds(
        (const __attribute__((address_space(1))) unsigned int*)g,
        (__attribute__((address_space(3))) unsigned int*)l,
        16, 0, 0);
}

// ------------------------------------------------------------------
// Shared MFMA GEMM body (64x64 tile, BK=64, 4 waves, dbuf LDS,
// 2-phase prefetch, XOR-swizzled LDS both-sides).
// EPI: 1 = fp32 out + qkvt col-activation + bias + bf16 raw-v copy
//          (omega=sigmoid*PI | amp=sigmoid/sqrtD | ph=tanh*PI | cr)
//      3 = fp32 partial out, no bias
//      4 = bf16 out, no bias
// NOTE (round-8 post-mortem): do NOT fuse split-K reduce via
// __threadfence + semaphore — device-scope fences cost ~45us across
// 256 blocks on gfx950 (cross-XCD L2 writeback). Separate dispatch wins.
// ------------------------------------------------------------------
template<int EPI>
__device__ __forceinline__ void gemm_body(
    const unsigned short* __restrict__ Ablk, int lda,
    const unsigned short* __restrict__ Btblk, int ldb,
    const float* __restrict__ bias,
    void* __restrict__ Cout, int ldc,
    int row0, int col0, int nk,
    unsigned short (*As)[4096], unsigned short (*Bs)[4096],
    unsigned short* __restrict__ aux = nullptr)
{
    const int tid = threadIdx.x;
    const int lane = tid & 63, wave = tid >> 6;
    const int wr = wave >> 1, wc = wave & 1;
    const int rowA = tid >> 3;                               // 0..31
    const int sb = ((tid & 7) << 4) ^ ((rowA & 7) << 4);     // swizzled byte-in-row
    const size_t offA0 = (size_t)rowA * lda + (sb >> 1);
    const size_t offA1 = offA0 + (size_t)32 * lda;
    const size_t offB0 = (size_t)rowA * ldb + (sb >> 1);
    const size_t offB1 = offB0 + (size_t)32 * ldb;
    const unsigned ldsO0 = wave * 1024u, ldsO1 = ldsO0 + 4096u;

    const int fr = lane & 15, grp = lane >> 4;
    int aA[2][2], aB[2][2];
    #pragma unroll
    for (int kk = 0; kk < 2; ++kk)
        #pragma unroll
        for (int f = 0; f < 2; ++f) {
            int ra = wr * 32 + f * 16 + fr;
            int rb = wc * 32 + f * 16 + fr;
            aA[f][kk] = (ra * 128 + kk * 64 + grp * 16) ^ ((ra & 7) << 4);
            aB[f][kk] = (rb * 128 + kk * 64 + grp * 16) ^ ((rb & 7) << 4);
        }

    auto stage = [&](int buf, int k0) {
        char* ab = (char*)As[buf]; char* bb = (char*)Bs[buf];
        gload16(Ablk  + offA0 + k0, ab + ldsO0);
        gload16(Ablk  + offA1 + k0, ab + ldsO1);
        gload16(Btblk + offB0 + k0, bb + ldsO0);
        gload16(Btblk + offB1 + k0, bb + ldsO1);
    };

    stage(0, 0);
    __syncthreads();
    f32x4 acc[2][2] = {};
    int cur = 0;
    for (int t = 0; t < nk; ++t) {
        if (t + 1 < nk) stage(cur ^ 1, (t + 1) * 64);
        const char* AsB = (const char*)As[cur];
        const char* BsB = (const char*)Bs[cur];
        #pragma unroll
        for (int kk = 0; kk < 2; ++kk) {
            short8 a0 = *(const short8*)(AsB + aA[0][kk]);
            short8 a1 = *(const short8*)(AsB + aA[1][kk]);
            short8 b0 = *(const short8*)(BsB + aB[0][kk]);
            short8 b1 = *(const short8*)(BsB + aB[1][kk]);
            acc[0][0] = __builtin_amdgcn_mfma_f32_16x16x32_bf16(a0, b0, acc[0][0], 0, 0, 0);
            acc[0][1] = __builtin_amdgcn_mfma_f32_16x16x32_bf16(a0, b1, acc[0][1], 0, 0, 0);
            acc[1][0] = __builtin_amdgcn_mfma_f32_16x16x32_bf16(a1, b0, acc[1][0], 0, 0, 0);
            acc[1][1] = __builtin_amdgcn_mfma_f32_16x16x32_bf16(a1, b1, acc[1][1], 0, 0, 0);
        }
        __syncthreads();
        cur ^= 1;
    }

    const int erow = row0 + wr * 32 + grp * 4;
    const int ecol = col0 + wc * 32 + fr;
    #pragma unroll
    for (int fm = 0; fm < 2; ++fm)
        #pragma unroll
        for (int fn = 0; fn < 2; ++fn)
            #pragma unroll
            for (int j = 0; j < 4; ++j) {
                int r = erow + fm * 16 + j;
                int c = ecol + fn * 16;
                float v = acc[fm][fn][j];
                if (EPI == 1) {
                    v += bias[c];
                    float outv = v;
                    if (c < 512)        outv = PI_F / (1.f + __expf(-v));          // omega
                    else if (c < 1024)  outv = INV_SQRT_D / (1.f + __expf(-v));    // amp/sqrtD
                    else if (c < 1536) {                                           // ph = tanh*PI
                        aux[(size_t)r * 512 + (c - 1024)] = f2bf(v);               // raw v for PV
                        outv = tanhf(v) * PI_F;
                    }
                    ((float*)Cout)[(size_t)r * ldc + c] = outv;
                } else if (EPI == 4) {
                    ((unsigned short*)Cout)[(size_t)r * ldc + c] = f2bf(v);
                } else {
                    ((float*)Cout)[(size_t)r * ldc + c] = v;
                }
            }
}

// ------------------------------------------------------------------
// Conv-as-GEMM body, split-K=8; A read from zero-padded xpad[B][264][512]
// (xpad row = s + tap; k = tap*512 + i). fp32 partials to convP[z].
// ------------------------------------------------------------------
__device__ __forceinline__ void conv_body(
    const unsigned short* __restrict__ xpad,
    const unsigned short* __restrict__ WbigT,
    float* __restrict__ convP, int bm, int bn, int z,
    unsigned short (*As)[4096], unsigned short (*Bs)[4096])
{
    const int tid = threadIdx.x;
    const int lane = tid & 63, wave = tid >> 6;
    const int wr = wave >> 1, wc = wave & 1;
    const int rowA = tid >> 3;
    const int sb = ((tid & 7) << 4) ^ ((rowA & 7) << 4);
    const int sbk = sb >> 1;
    const int r0 = bm * 64 + rowA;
    const int base0 = ((r0 >> 8) * 264 + (r0 & 255)) * 512;
    const int r1 = r0 + 32;
    const int base1 = ((r1 >> 8) * 264 + (r1 & 255)) * 512;
    const size_t offB0 = (size_t)(bn * 64 + rowA) * 4608 + sbk;
    const size_t offB1 = offB0 + (size_t)32 * 4608;
    const unsigned ldsO0 = wave * 1024u, ldsO1 = ldsO0 + 4096u;
    const int kstart = z * 576;              // 4608 / 8

    const int fr = lane & 15, grp = lane >> 4;
    int aA[2][2], aB[2][2];
    #pragma unroll
    for (int kk = 0; kk < 2; ++kk)
        #pragma unroll
        for (int f = 0; f < 2; ++f) {
            int ra = wr * 32 + f * 16 + fr;
            int rb = wc * 32 + f * 16 + fr;
            aA[f][kk] = (ra * 128 + kk * 64 + grp * 16) ^ ((ra & 7) << 4);
            aB[f][kk] = (rb * 128 + kk * 64 + grp * 16) ^ ((rb & 7) << 4);
        }

    auto stage = [&](int buf, int k0) {
        int tap = k0 >> 9;
        int ro = tap * 512 + (k0 & 511) + sbk;
        char* ab = (char*)As[buf]; char* bb = (char*)Bs[buf];
        gload16(xpad + base0 + ro, ab + ldsO0);
        gload16(xpad + base1 + ro, ab + ldsO1);
        gload16(WbigT + offB0 + k0, bb + ldsO0);
        gload16(WbigT + offB1 + k0, bb + ldsO1);
    };

    stage(0, kstart);
    __syncthreads();
    f32x4 acc[2][2] = {};
    int cur = 0;
    for (int t = 0; t < 9; ++t) {
        if (t < 8) stage(cur ^ 1, kstart + (t + 1) * 64);
        const char* AsB = (const char*)As[cur];
        const char* BsB = (const char*)Bs[cur];
        #pragma unroll
        for (int kk = 0; kk < 2; ++kk) {
            short8 a0 = *(const short8*)(AsB + aA[0][kk]);
            short8 a1 = *(const short8*)(AsB + aA[1][kk]);
            short8 b0 = *(const short8*)(BsB + aB[0][kk]);
            short8 b1 = *(const short8*)(BsB + aB[1][kk]);
            acc[0][0] = __builtin_amdgcn_mfma_f32_16x16x32_bf16(a0, b0, acc[0][0], 0, 0, 0);
            acc[0][1] = __builtin_amdgcn_mfma_f32_16x16x32_bf16(a0, b1, acc[0][1], 0, 0, 0);
            acc[1][0] = __builtin_amdgcn_mfma_f32_16x16x32_bf16(a1, b0, acc[1][0], 0, 0, 0);
            acc[1][1] = __builtin_amdgcn_mfma_f32_16x16x32_bf16(a1, b1, acc[1][1], 0, 0, 0);
        }
        __syncthreads();
        cur ^= 1;
    }

    float* Cp = convP + (size_t)z * 262144;
    const int erow = bm * 64 + wr * 32 + grp * 4;
    const int ecol = bn * 64 + wc * 32 + fr;
    #pragma unroll
    for (int fm = 0; fm < 2; ++fm)
        #pragma unroll
        for (int fn = 0; fn < 2; ++fn)
            #pragma unroll
            for (int j = 0; j < 4; ++j)
                Cp[(size_t)(erow + fm * 16 + j) * 512 + ecol + fn * 16] = acc[fm][fn][j];
}

// ------------------------------------------------------------------
// Dispatch 1: all prep. Segments by blockIdx (latency-bound FIRST):
// [0,64)        bias_effP[64][512]: block bb covers 24 k's of
//               [bo|bwl|bfc] @ Wproj, fully unrolled
// [64,1088)     WbigT: thread per (o,i), all taps contiguous
// [1088,3136)   32x32-tile transposes: WcatT (1280), WprojT (768)
// [3136,3400)   xpad (zero-padded bf16 x), 4/thread
// [3400,4424)   flat bf16 converts: Wo_b | Wwl_b | Wfc_b, 4/thread
// [4424,4438)   bcat1 + beff + per-channel sincos(phase_shifts)
// ------------------------------------------------------------------
__global__ __launch_bounds__(256)
void prep_all(const float* __restrict__ x,
              const float* __restrict__ Wq, const float* __restrict__ Wk,
              const float* __restrict__ Wv, const float* __restrict__ Wtc,
              const float* __restrict__ Wo, const float* __restrict__ Wwl,
              const float* __restrict__ Wfc, const float* __restrict__ Wproj,
              const float* __restrict__ cw1, const float* __restrict__ cw2,
              const float* __restrict__ cw3, const float* __restrict__ scale_w,
              const float* __restrict__ bq, const float* __restrict__ bk,
              const float* __restrict__ bv, const float* __restrict__ btc,
              const float* __restrict__ cb1, const float* __restrict__ cb2,
              const float* __restrict__ cb3,
              const float* __restrict__ bo, const float* __restrict__ bwl,
              const float* __restrict__ bfc, const float* __restrict__ phase_shifts,
              unsigned short* __restrict__ xpad, unsigned short* __restrict__ WcatT,
              unsigned short* __restrict__ WbigT, unsigned short* __restrict__ WprojT,
              unsigned short* __restrict__ Wo_b, unsigned short* __restrict__ Wwl_b,
              unsigned short* __restrict__ Wfc_b,
              float* __restrict__ bcat1, float* __restrict__ beff,
              float* __restrict__ cps, float* __restrict__ sps,
              float* __restrict__ bias_effP)
{
    int bid = blockIdx.x, tid = threadIdx.x;

    if (bid < 64) {                         // bias_effP[bb][512], 24 k's each
        int k0 = bid * 24;
        float a0 = 0.f, a1 = 0.f;
        #pragma unroll
        for (int m = 0; m < 24; ++m) {
            int k = k0 + m;
            float w = (k < 512) ? bo[k] : (k < 1024) ? bwl[k - 512] : bfc[k - 1024];
            a0 = fmaf(w, Wproj[(size_t)k * 512 + tid], a0);
            a1 = fmaf(w, Wproj[(size_t)k * 512 + tid + 256], a1);
        }
        bias_effP[(size_t)bid * 512 + tid] = a0;
        bias_effP[(size_t)bid * 512 + tid + 256] = a1;
        return;
    }
    bid -= 64;
    if (bid < 1024) {                       // WbigT [512 o][4608 = t*512+i]
        int oi = bid * 256 + tid;           // < 262144
        int o = oi >> 9, i = oi & 511;
        float w0, w1, w2; softmax3(scale_w, w0, w1, w2);
        float wt[9];
        #pragma unroll
        for (int t = 0; t < 9; ++t) wt[t] = w2 * cw3[(size_t)oi * 9 + t];
        #pragma unroll
        for (int t = 0; t < 3; ++t) wt[t + 3] = fmaf(w0, cw1[(size_t)oi * 3 + t], wt[t + 3]);
        #pragma unroll
        for (int t = 0; t < 5; ++t) wt[t + 2] = fmaf(w1, cw2[(size_t)oi * 5 + t], wt[t + 2]);
        unsigned short* dst = WbigT + (size_t)o * 4608 + i;
        #pragma unroll
        for (int t = 0; t < 9; ++t) dst[t * 512] = f2bf(wt[t]);   // coalesced across lanes
        return;
    }
    bid -= 1024;
    if (bid < 2048) {                       // transposes
        __shared__ float tile[32][33];
        int t = bid;
        const float* src; unsigned short* dst;
        int srcld, dstld, ntk, drow0;
        if (t < 256)       {            src = Wq;    srcld = 512;  dst = WcatT;  dstld = 512;  ntk = 16; drow0 = 0; }
        else if (t < 512)  { t -= 256;  src = Wk;    srcld = 512;  dst = WcatT;  dstld = 512;  ntk = 16; drow0 = 512; }
        else if (t < 768)  { t -= 512;  src = Wv;    srcld = 512;  dst = WcatT;  dstld = 512;  ntk = 16; drow0 = 1024; }
        else if (t < 1280) { t -= 768;  src = Wtc;   srcld = 1024; dst = WcatT;  dstld = 512;  ntk = 16; drow0 = 1536; }
        else               { t -= 1280; src = Wproj; srcld = 512;  dst = WprojT; dstld = 1536; ntk = 48; drow0 = 0; }
        int tk = t % ntk, tn = t / ntk;
        int r8 = tid >> 5, c = tid & 31;
        #pragma unroll
        for (int rr = 0; rr < 4; ++rr) {
            int r = r8 + rr * 8;
            tile[r][c] = src[(size_t)(tk * 32 + r) * srcld + tn * 32 + c];
        }
        __syncthreads();
        #pragma unroll
        for (int rr = 0; rr < 4; ++rr) {
            int r = r8 + rr * 8;
            dst[(size_t)(drow0 + tn * 32 + r) * dstld + tk * 32 + c] = f2bf(tile[c][r]);
        }
        return;
    }
    bid -= 2048;
    if (bid < 264) {                        // xpad[B][264][512]
        int e = bid * 1024 + tid * 4;       // < 270336
        int b = e / 135168, rem = e - b * 135168;
        int srow = rem >> 9, i4 = rem & 511;
        int s2 = srow - 4;
        ushort4v pk = {0, 0, 0, 0};
        if (s2 >= 0 && s2 < 256) {
            f32x4 v = *(const f32x4*)&x[((size_t)(b * 256 + s2) << 9) + i4];
            pk[0] = f2bf(v[0]); pk[1] = f2bf(v[1]); pk[2] = f2bf(v[2]); pk[3] = f2bf(v[3]);
        }
        *(ushort4v*)&xpad[e] = pk;
        return;
    }
    bid -= 264;
    if (bid < 1024) {                       // Wo_b | Wwl_b | Wfc_b flat converts
        int f = bid * 1024 + tid * 4;       // < 1048576
        const float* src; unsigned short* dst; int o;
        if (f < 262144)      { src = Wo;  dst = Wo_b;  o = f; }
        else if (f < 524288) { src = Wwl; dst = Wwl_b; o = f - 262144; }
        else                 { src = Wfc; dst = Wfc_b; o = f - 524288; }
        f32x4 v = *(const f32x4*)&src[o];
        ushort4v pk;
        pk[0] = f2bf(v[0]); pk[1] = f2bf(v[1]); pk[2] = f2bf(v[2]); pk[3] = f2bf(v[3]);
        *(ushort4v*)&dst[o] = pk;
        return;
    }
    bid -= 1024;
    {                                       // bcat1 + beff + phase-shift table
        int idx = bid * 256 + tid;
        if (idx < 2560) {
            float v;
            if (idx < 512)       v = bq[idx];
            else if (idx < 1024) v = bk[idx - 512];
            else if (idx < 1536) v = bv[idx - 1024];
            else                 v = btc[idx - 1536];
            bcat1[idx] = v;
        } else if (idx < 3072) {
            int c = idx - 2560;
            float w0, w1, w2; softmax3(scale_w, w0, w1, w2);
            beff[c] = w0 * cb1[c] + w1 * cb2[c] + w2 * cb3[c];
        } else if (idx < 3584) {
            int c = idx - 3072;
            float sn, cn; sincosf(phase_shifts[c], &sn, &cn);
            cps[c] = cn; sps[c] = sn;
        }
    }
}

// ------------------------------------------------------------------
// Dispatch 2: all weight-side + input-side big GEMMs concurrently.
// [0,512)     conv split-K=8 partials
// [512,832)   qkvt = xpad @ WcatT (+bias/acts; bf16 raw-v copy)
// [832,896)   WeffCat_T[:, 0:512]    = WprojT[:,0:512]    @ Wo^T
// [896,960)   WeffCat_T[:, 512:1024] = WprojT[:,512:1024] @ Wwl^T
// [960,1088)  WeffCat_T[:,1024:2048] = WprojT[:,1024:1536]@ Wfc^T
// ------------------------------------------------------------------
__global__ __launch_bounds__(256)
void big_gemms(const unsigned short* __restrict__ xpad,
               const unsigned short* __restrict__ WbigT, float* __restrict__ convP,
               const unsigned short* __restrict__ WcatT, const float* __restrict__ bcat1,
               float* __restrict__ qkvt, unsigned short* __restrict__ vb16,
               const unsigned short* __restrict__ WprojT,
               const unsigned short* __restrict__ Wo_b, const unsigned short* __restrict__ Wwl_b,
               const unsigned short* __restrict__ Wfc_b,
               unsigned short* __restrict__ WeffCat_T)
{
    __shared__ unsigned short As[2][4096], Bs[2][4096];
    int bid = blockIdx.x;
    if (bid < 512) {
        conv_body(xpad, WbigT, convP, (bid >> 3) & 7, bid & 7, bid >> 6, As, Bs);
        return;
    }
    bid -= 512;
    if (bid < 320) {
        int bm = bid / 40, bn = bid % 40;
        int r0 = bm * 64;
        const unsigned short* Axp = xpad + ((size_t)(r0 >> 8) * 264 + (r0 & 255) + 4) * 512;
        gemm_body<1>(Axp, 512, WcatT + (size_t)bn * 64 * 512, 512, bcat1,
                     qkvt, 2560, r0, bn * 64, 8, As, Bs, vb16);
        return;
    }
    bid -= 320;
    if (bid < 64) {
        int bm = bid >> 3, bn = bid & 7;
        gemm_body<4>(WprojT + (size_t)bm * 64 * 1536, 1536, Wo_b + (size_t)bn * 64 * 512, 512,
                     nullptr, WeffCat_T, 2048, bm * 64, bn * 64, 8, As, Bs);
        return;
    }
    bid -= 64;
    if (bid < 64) {
        int bm = bid >> 3, bn = bid & 7;
        gemm_body<4>(WprojT + 512 + (size_t)bm * 64 * 1536, 1536, Wwl_b + (size_t)bn * 64 * 512, 512,
                     nullptr, WeffCat_T + 512, 2048, bm * 64, bn * 64, 8, As, Bs);
        return;
    }
    bid -= 64;
    {   // Wfc part: M=512 (j), N=1024 (nc-channel), K=512
        int bm = bid >> 4, bn = bid & 15;
        gemm_body<4>(WprojT + 1024 + (size_t)bm * 64 * 1536, 1536, Wfc_b + (size_t)bn * 64 * 512, 512,
                     nullptr, WeffCat_T + 1024, 2048, bm * 64, bn * 64, 8, As, Bs);
    }
}

// ------------------------------------------------------------------
// Dispatch 3: branch nonlinears -> A_cat [512 rows][2048] bf16.
// [0,1024)     attn (cos recurrence; 1 exp/iter; tanh/scale pre-applied)
// [1024,2048)  phase (transcendental-free: rsqrt + Taylor rotation)
// [2048,3072)  conv split-K=8 reduce
// [3072,3074)  bias_eff[j] = bproj[j] + sum_64 bias_effP[p][j]
// ------------------------------------------------------------------
__global__ __launch_bounds__(256)
void branches(const float* __restrict__ qkvt, const unsigned short* __restrict__ vb16,
              const float* __restrict__ cps, const float* __restrict__ sps,
              const float* __restrict__ convP, const float* __restrict__ beff,
              const float* __restrict__ bias_effP, const float* __restrict__ bproj,
              unsigned short* __restrict__ A_cat, float* __restrict__ bias_eff)
{
    int bid = blockIdx.x, tid = threadIdx.x;
    if (bid < 1024) {                       // wave attention
        const int bi = bid >> 1;
        const int b = bi >> 8, i = bi & 255;
        const int c = ((bid & 1) << 8) + tid;
        const float* qrow = qkvt + (size_t)bi * 2560;
        const float om = qrow[c];
        const float am = qrow[512 + c];          // sigmoid/sqrtD pre-applied
        const float ph = qrow[1024 + c];         // tanh*PI pre-applied
        float cosom, sinom, cc, ss;
        sincosf(om, &sinom, &cosom);
        sincosf(fmaf(om, (float)i, ph), &ss, &cc);   // ang at j=0
        const unsigned short* vb = vb16 + (size_t)(b * 256) * 512 + c;
        float se = 0.f, sev = 0.f;
        #pragma unroll 4
        for (int j = 0; j < 256; ++j) {
            float e = __expf(am * cc);
            se += e;
            sev = fmaf(e, bf2f(vb[(size_t)j * 512]), sev);
            float cn = fmaf(cc, cosom, ss * sinom);  // cos(ang - om)
            ss = fmaf(ss, cosom, -cc * sinom);       // sin(ang - om)
            cc = cn;
        }
        A_cat[(size_t)bi * 2048 + c] = f2bf(sev / se);
        return;
    }
    bid -= 1024;
    if (bid < 1024) {                       // phase branch, trans-free
        const int b = bid >> 9, c = bid & 511;
        const int s = tid;
        const float* row = qkvt + (size_t)(b * 256 + s) * 2560 + 1536;
        float re = row[c], im = row[c + 512];
        float hyp2 = fmaf(re, re, im * im);
        float mag = sqrtf(hyp2 + 1e-5f);
        float rh = rsqrtf(fmaxf(hyp2, 1e-30f));
        float cp = re * rh, sp = im * rh;            // cos(p), sin(p)
        float cs = cp, sn = sp;
        #pragma unroll
        for (int m = 32; m; m >>= 1) { cs += __shfl_xor(cs, m); sn += __shfl_xor(sn, m); }
        __shared__ float wred[8];
        int w = s >> 6, l = s & 63;
        if (l == 0) { wred[w] = cs; wred[4 + w] = sn; }
        __syncthreads();
        float mcv = (wred[0] + wred[1] + wred[2] + wred[3]) * (1.f / 256.f);
        float msv = (wred[4] + wred[5] + wred[6] + wred[7]) * (1.f / 256.f);
        float cq = cps[c], sq = sps[c];
        float cpps = cp * cq - sp * sq;              // cos(p+psh)
        float spps = sp * cq + cp * sq;              // sin(p+psh)
        float d = 0.1f * (cpps * mcv + spps * msv);  // |d| <= 0.2
        float d2 = d * d;
        float cosd = 1.f - d2 * (0.5f - d2 * (1.f / 24.f));
        float sind = d * (1.f - d2 * ((1.f / 6.f) - d2 * (1.f / 120.f)));
        float cnp = cp * cosd - sp * sind;           // cos(p + d)
        float snp = sp * cosd + cp * sind;
        size_t o = (size_t)(b * 256 + s) * 2048 + c;
        A_cat[o + 1024] = f2bf(mag * cnp);
        A_cat[o + 1536] = f2bf(mag * snp);
        return;
    }
    bid -= 1024;
    if (bid < 1024) {                       // conv reduce (8 slices)
        int idx = bid * 256 + tid;
        int r = idx >> 9, c = idx & 511;
        float v = beff[c];
        #pragma unroll
        for (int z = 0; z < 8; ++z) v += convP[idx + (size_t)z * 262144];
        A_cat[(size_t)r * 2048 + 512 + c] = f2bf(v);
        return;
    }
    bid -= 1024;
    {                                       // bias_eff reduce (2 blocks)
        int j = bid * 256 + tid;
        float acc = bproj[j];
        #pragma unroll
        for (int p = 0; p < 64; ++p) acc += bias_effP[(size_t)p * 512 + j];
        bias_eff[j] = acc;
    }
}

// ------------------------------------------------------------------
// Dispatch 4: fused output GEMM, K=2048, split-K=8 (512 blocks x 4 steps).
// P[z] = A_cat[:, z*256:(z+1)*256] @ WeffCat_T[:, z*256:(z+1)*256]^T
// ------------------------------------------------------------------
__global__ __launch_bounds__(256)
void mid_gemm(const unsigned short* __restrict__ A_cat,
              const unsigned short* __restrict__ WeffCat_T,
              float* __restrict__ P)
{
    __shared__ unsigned short As[2][4096], Bs[2][4096];
    int bid = blockIdx.x;
    int z = bid >> 6, bm = (bid >> 3) & 7, bn = bid & 7;
    gemm_body<3>(A_cat + (size_t)bm * 64 * 2048 + z * 256, 2048,
                 WeffCat_T + (size_t)bn * 64 * 2048 + z * 256, 2048,
                 nullptr, P + (size_t)z * 262144, 512, bm * 64, bn * 64, 4, As, Bs);
}

// ------------------------------------------------------------------
// Dispatch 5: sum 8 P partials + bias_eff + residual + LayerNorm
// ------------------------------------------------------------------
__global__ __launch_bounds__(256)
void final_ln(const float* __restrict__ x, const float* __restrict__ P,
              const float* __restrict__ bias_eff,
              const float* __restrict__ g, const float* __restrict__ bta,
              float* __restrict__ out)
{
    int r = blockIdx.x, t = threadIdx.x;
    size_t o0 = (size_t)r * 512 + t, o1 = o0 + 256;
    float c0 = bias_eff[t], c1 = bias_eff[t + 256];
    #pragma unroll
    for (int z = 0; z < 8; ++z) {
        c0 += P[o0 + (size_t)z * 262144];
        c1 += P[o1 + (size_t)z * 262144];
    }
    float v0 = x[o0] + c0, v1 = x[o1] + c1;
    float sum = v0 + v1;
    #pragma unroll
    for (int m = 32; m; m >>= 1) sum += __shfl_xor(sum, m);
    __shared__ float wred[8];
    int w = t >> 6, l = t & 63;
    if (l == 0) wred[w] = sum;
    __syncthreads();
    float mu = (wred[0] + wred[1] + wred[2] + wred[3]) * (1.f / 512.f);
    float d0 = v0 - mu, d1 = v1 - mu;
    float s2 = d0 * d0 + d1 * d1;
    #pragma unroll
    for (int m = 32; m; m >>= 1) s2 += __shfl_xor(s2, m);
    if (l == 0) wred[4 + w] = s2;
    __syncthreads();
    float inv = rsqrtf((wred[4] + wred[5] + wred[6] + wred[7]) * (1.f / 512.f) + 1e-5f);
    out[o0] = d0 * inv * g[t]       + bta[t];
    out[o1] = d1 * inv * g[t + 256] + bta[t + 256];
}

// ------------------------------------------------------------------
extern "C" void kernel_launch(void* const* d_in, const int* in_sizes, int n_in,
                              void* d_out, int out_size, void* d_ws, size_t ws_size,
                              hipStream_t stream)
{
    const float* x   = (const float*)d_in[0];
    const float* Wq  = (const float*)d_in[1];
    const float* bq  = (const float*)d_in[2];
    const float* Wk  = (const float*)d_in[3];
    const float* bk  = (const float*)d_in[4];
    const float* Wv  = (const float*)d_in[5];
    const float* bv  = (const float*)d_in[6];
    const float* Wo  = (const float*)d_in[7];
    const float* bo  = (const float*)d_in[8];
    const float* cw1 = (const float*)d_in[9];
    const float* cb1 = (const float*)d_in[10];
    const float* cw2 = (const float*)d_in[11];
    const float* cb2 = (const float*)d_in[12];
    const float* cw3 = (const float*)d_in[13];
    const float* cb3 = (const float*)d_in[14];
    const float* scale_w = (const float*)d_in[15];
    const float* Wwl = (const float*)d_in[16];
    const float* bwl = (const float*)d_in[17];
    const float* Wtc = (const float*)d_in[18];
    const float* btc = (const float*)d_in[19];
    const float* Wfc = (const float*)d_in[20];
    const float* bfc = (const float*)d_in[21];
    const float* phase_shifts = (const float*)d_in[22];
    const float* Wproj = (const float*)d_in[23];
    const float* bproj = (const float*)d_in[24];
    const float* ln_g = (const float*)d_in[25];
    const float* ln_b = (const float*)d_in[26];
    float* out = (float*)d_out;

    // ---- workspace layout ----
    float* wsf       = (float*)d_ws;
    float* qkvt      = wsf;                     // 1,310,720 f
    float* convP     = qkvt + 1310720;          // 2,097,152 f (8 x 512x512)
    float* P         = convP + 2097152;         // 2,097,152 f (8 x 512x512)
    float* bias_effP = P + 2097152;             //    32,768 f (64 x 512)
    float* bias_eff  = bias_effP + 32768;       //       512 f
    float* bcat1     = bias_eff + 512;          //     2,560 f
    float* beff      = bcat1 + 2560;            //       512 f
    float* cps       = beff + 512;              //       512 f
    float* sps       = cps + 512;               //       512 f
    unsigned short* u = (unsigned short*)(sps + 512);
    unsigned short* xpad     = u;                    // 270,336
    unsigned short* WcatT    = xpad + 270336;        // 1,310,720
    unsigned short* WbigT    = WcatT + 1310720;      // 2,359,296
    unsigned short* WprojT   = WbigT + 2359296;      // 786,432
    unsigned short* Wo_b     = WprojT + 786432;      // 262,144
    unsigned short* Wwl_b    = Wo_b + 262144;        // 262,144
    unsigned short* Wfc_b    = Wwl_b + 262144;       // 524,288
    unsigned short* WeffCat_T= Wfc_b + 524288;       // 1,048,576 ([512][2048])
    unsigned short* A_cat    = WeffCat_T + 1048576;  // 1,048,576 ([512][2048])
    unsigned short* vb16     = A_cat + 1048576;      // 262,144

    prep_all<<<4438, 256, 0, stream>>>(x, Wq, Wk, Wv, Wtc, Wo, Wwl, Wfc, Wproj,
                                       cw1, cw2, cw3, scale_w,
                                       bq, bk, bv, btc, cb1, cb2, cb3,
                                       bo, bwl, bfc, phase_shifts,
                                       xpad, WcatT, WbigT, WprojT,
                                       Wo_b, Wwl_b, Wfc_b,
                                       bcat1, beff, cps, sps, bias_effP);

    big_gemms<<<1088, 256, 0, stream>>>(xpad, WbigT, convP, WcatT, bcat1, qkvt, vb16,
                                        WprojT, Wo_b, Wwl_b, Wfc_b, WeffCat_T);

    branches<<<3074, 256, 0, stream>>>(qkvt, vb16, cps, sps, convP, beff,
                                       bias_effP, bproj, A_cat, bias_eff);

    mid_gemm<<<512, 256, 0, stream>>>(A_cat, WeffCat_T, P);

    final_ln<<<512, 256, 0, stream>>>(x, P, bias_eff, ln_g, ln_b, out);
}